// Round 3
// baseline (475.880 us; speedup 1.0000x reference)
//
#include <hip/hip_runtime.h>
#include <math.h>

#define NDIM 4096
#define NNZ_C 110592
#define BATCH 128

typedef unsigned short ushort_t;
typedef __attribute__((ext_vector_type(4))) float f32x4;
typedef __attribute__((ext_vector_type(8))) short s16x8;
typedef __attribute__((ext_vector_type(4))) unsigned uint4v;

// ---------------------------------------------------------------- helpers
__device__ __forceinline__ float selu_f(float x) {
    const float scale = 1.0507009873554804934193349852946f;
    const float alpha = 1.6732632423543772848170429916717f;
    return x > 0.0f ? scale * x : scale * alpha * expm1f(x);
}

// pack 2 f32 -> 2 bf16 (RTNE): low16 = bf16(a), high16 = bf16(b)
__device__ __forceinline__ unsigned cvt_pk_bf16(float a, float b) {
    unsigned r;
    asm volatile("v_cvt_pk_bf16_f32 %0, %1, %2" : "=v"(r) : "v"(a), "v"(b));
    return r;
}

// ---------------------------------------------------------------- 1) transpose x [128][4096] -> xt [4096][128]
__global__ __launch_bounds__(256) void k_transpose(const float* __restrict__ x,
                                                   float* __restrict__ xt) {
    __shared__ float tile[32][33];
    int bn = blockIdx.x, bb = blockIdx.y;
    int tx = threadIdx.x & 31, ty = threadIdx.x >> 5;
#pragma unroll
    for (int i = 0; i < 4; ++i)
        tile[ty + i * 8][tx] = x[(size_t)(bb * 32 + ty + i * 8) * NDIM + bn * 32 + tx];
    __syncthreads();
#pragma unroll
    for (int i = 0; i < 4; ++i)
        xt[(size_t)(bn * 32 + ty + i * 8) * BATCH + bb * 32 + tx] = tile[tx][ty + i * 8];
}

// ---------------------------------------------------------------- 2) COO spmv via LDS accumulation
// grid (32 batch-quads, 4 nnz-slices). Block accumulates y[n][4] for its quad in LDS,
// dumps its private slice to y_p[(j*32+q)][4096][4]. No global atomics.
__global__ __launch_bounds__(256) void k_spmv(const int* __restrict__ rows,
                                              const int* __restrict__ cols,
                                              const float* __restrict__ vals,
                                              const float* __restrict__ xt,
                                              float* __restrict__ y_p) {
    __shared__ float yl[NDIM * 4];
    const int t = threadIdx.x, q = blockIdx.x, j = blockIdx.y;
#pragma unroll
    for (int i = 0; i < 16; ++i)
        *(f32x4*)(yl + i * 1024 + t * 4) = (f32x4){0.f, 0.f, 0.f, 0.f};
    __syncthreads();
    const int base = j * (NNZ_C / 4);
    for (int i = 0; i < (NNZ_C / 4) / 256; ++i) {   // 108 exact
        int e = base + i * 256 + t;
        int r = rows[e], c = cols[e];
        float v = vals[e];
        f32x4 xv = *(const f32x4*)(xt + (size_t)c * BATCH + q * 4);
        atomicAdd(&yl[r * 4 + 0], v * xv[0]);
        atomicAdd(&yl[r * 4 + 1], v * xv[1]);
        atomicAdd(&yl[r * 4 + 2], v * xv[2]);
        atomicAdd(&yl[r * 4 + 3], v * xv[3]);
    }
    __syncthreads();
    float* dst = y_p + (size_t)(j * 32 + q) * (NDIM * 4);
#pragma unroll
    for (int i = 0; i < 16; ++i)
        *(f32x4*)(dst + i * 1024 + t * 4) = *(const f32x4*)(yl + i * 1024 + t * 4);
}

// ---------------------------------------------------------------- 3) reduce partials + bc/flag + hi/lo split -> A-frag layout
// Ahi/Alo: [(m>>3)*128 + b]*8 + (m&7)
__global__ __launch_bounds__(256) void k_prep(const float* __restrict__ y_p,
                                              const float* __restrict__ bc,
                                              const float* __restrict__ flag,
                                              ushort_t* __restrict__ Ahi,
                                              ushort_t* __restrict__ Alo) {
    int idx = blockIdx.x * 256 + threadIdx.x;   // 65536
    int kc = idx >> 7, b = idx & 127;
    int q = b >> 2, bl = b & 3;
    s16x8 hv, lv;
#pragma unroll
    for (int u = 0; u < 8; ++u) {
        int m = kc * 8 + u;
        float s = 0.f;
#pragma unroll
        for (int j = 0; j < 4; ++j)
            s += y_p[((size_t)(j * 32 + q) * NDIM + m) * 4 + bl];
        float v = bc[m] + s * flag[m];
        unsigned h = cvt_pk_bf16(v, v);
        float res = v - __uint_as_float(h << 16);
        unsigned lw = cvt_pk_bf16(res, res);
        hv[u] = (short)(h & 0xffffu);
        lv[u] = (short)(lw & 0xffffu);
    }
    *(s16x8*)(Ahi + ((size_t)kc * BATCH + b) * 8) = hv;
    *(s16x8*)(Alo + ((size_t)kc * BATCH + b) * 8) = lv;
}

// ---------------------------------------------------------------- 4) fused GEMM, k-split, bf16x3 fp32 emulation
// grid (256 n-tiles, KS kq). 256 thr = 4 waves; wave w = batch rows [w*32, w*32+32) (2 MFMA tiles).
// Per 128-k iter: W1 tile (48 rows x 128 k) -> regs (6 dwordx4/thread) -> split -> LDS bf16
// frag-chunk layout: chunk C in [0,768): plane P=C>>6 (s=P>>2, c32=P&3), cp=C&63 (n=cp&15, k8=cp>>4)
// hi at byte C*16, lo at 12288+C*16. Writes AND mfma reads are lane-contiguous (0 conflicts).
__global__ __launch_bounds__(256, 3) void k_gemm(const float* __restrict__ W1,
                                                 const ushort_t* __restrict__ Ahi,
                                                 const ushort_t* __restrict__ Alo,
                                                 float* __restrict__ t_p,
                                                 int klen) {
    __shared__ __align__(16) char lds[24576];
    const int tid = threadIdx.x;
    const int w = tid >> 6, l = tid & 63;
    const int lr = l & 15, lh = l >> 4;
    const int n0 = blockIdx.x * 16;
    const int kq = blockIdx.y;
    const int kbase = kq * klen;
    const int nit = klen >> 7;

    f32x4 acc[2][3];
#pragma unroll
    for (int t2 = 0; t2 < 2; ++t2)
#pragma unroll
        for (int s = 0; s < 3; ++s) acc[t2][s] = (f32x4){0.f, 0.f, 0.f, 0.f};

    // W source pointers per q-chunk
    const float* gq[3];
    int dst16[3];
#pragma unroll
    for (int q = 0; q < 3; ++q) {
        int C = tid + q * 256;
        int P = C >> 6, cp = C & 63;
        int s = P >> 2, c32 = P & 3;
        int n = cp & 15, k8 = cp >> 4;
        gq[q] = W1 + ((size_t)(s * NDIM + n0 + n)) * NDIM + kbase + c32 * 32 + k8 * 8;
        dst16[q] = C * 16;
    }

    // A-frag base offsets (elements): plane kcg is 1024 elements
    const size_t kcgb = (size_t)(kbase >> 3);
    size_t arow[2];
    arow[0] = (size_t)(w * 32 + lr) * 8;
    arow[1] = (size_t)(w * 32 + 16 + lr) * 8;

    f32x4 wA[6], wB[6];
    // prologue: issue W(0)
#pragma unroll
    for (int q = 0; q < 3; ++q) {
        wA[2 * q]     = *(const f32x4*)(gq[q]);
        wA[2 * q + 1] = *(const f32x4*)(gq[q] + 4);
    }

    auto STEP = [&](f32x4 (&wc)[6], f32x4 (&wn)[6], int it) {
        // barrier A: previous iter's mfma reads done (full drain harmless: only W(it) outstanding,
        // which split needs immediately anyway)
        __syncthreads();
        // split: 3 chunks -> 6 ds_write_b128
#pragma unroll
        for (int q = 0; q < 3; ++q) {
            f32x4 a = wc[2 * q], b = wc[2 * q + 1];
            unsigned h0 = cvt_pk_bf16(a[0], a[1]);
            unsigned h1 = cvt_pk_bf16(a[2], a[3]);
            unsigned h2 = cvt_pk_bf16(b[0], b[1]);
            unsigned h3 = cvt_pk_bf16(b[2], b[3]);
            float r0 = a[0] - __uint_as_float(h0 << 16);
            float r1 = a[1] - __uint_as_float(h0 & 0xffff0000u);
            float r2 = a[2] - __uint_as_float(h1 << 16);
            float r3 = a[3] - __uint_as_float(h1 & 0xffff0000u);
            float r4 = b[0] - __uint_as_float(h2 << 16);
            float r5 = b[1] - __uint_as_float(h2 & 0xffff0000u);
            float r6 = b[2] - __uint_as_float(h3 << 16);
            float r7 = b[3] - __uint_as_float(h3 & 0xffff0000u);
            unsigned l0 = cvt_pk_bf16(r0, r1);
            unsigned l1 = cvt_pk_bf16(r2, r3);
            unsigned l2 = cvt_pk_bf16(r4, r5);
            unsigned l3 = cvt_pk_bf16(r6, r7);
            *(uint4v*)(lds + dst16[q])         = (uint4v){h0, h1, h2, h3};
            *(uint4v*)(lds + 12288 + dst16[q]) = (uint4v){l0, l1, l2, l3};
        }
        // issue next W tile (register loads stay in flight across the raw barrier)
        if (it + 1 < nit) {
            const size_t moff = (size_t)(it + 1) * 128;
#pragma unroll
            for (int q = 0; q < 3; ++q) {
                wn[2 * q]     = *(const f32x4*)(gq[q] + moff);
                wn[2 * q + 1] = *(const f32x4*)(gq[q] + moff + 4);
            }
        }
        // barrier B: raw (no implicit vmcnt drain) -- writes made visible via lgkmcnt(0)
        __builtin_amdgcn_sched_barrier(0);
        asm volatile("s_waitcnt lgkmcnt(0)" ::: "memory");
        __builtin_amdgcn_s_barrier();
        __builtin_amdgcn_sched_barrier(0);

        // MFMA phase with one-c-ahead A prefetch
        const size_t kit = kcgb + (size_t)it * 16;
        s16x8 a_h[4][2], a_l[4][2];
#pragma unroll
        for (int t2 = 0; t2 < 2; ++t2) {
            a_h[0][t2] = *(const s16x8*)(Ahi + (kit + lh) * 1024 + arow[t2]);
            a_l[0][t2] = *(const s16x8*)(Alo + (kit + lh) * 1024 + arow[t2]);
        }
#pragma unroll
        for (int c = 0; c < 4; ++c) {
            if (c < 3) {
#pragma unroll
                for (int t2 = 0; t2 < 2; ++t2) {
                    a_h[c + 1][t2] = *(const s16x8*)(Ahi + (kit + (c + 1) * 4 + lh) * 1024 + arow[t2]);
                    a_l[c + 1][t2] = *(const s16x8*)(Alo + (kit + (c + 1) * 4 + lh) * 1024 + arow[t2]);
                }
            }
#pragma unroll
            for (int s = 0; s < 3; ++s) {
                s16x8 bhi = *(const s16x8*)(lds + (s * 4 + c) * 1024 + l * 16);
                s16x8 blo = *(const s16x8*)(lds + 12288 + (s * 4 + c) * 1024 + l * 16);
#pragma unroll
                for (int t2 = 0; t2 < 2; ++t2) {
                    acc[t2][s] = __builtin_amdgcn_mfma_f32_16x16x32_bf16(a_h[c][t2], bhi, acc[t2][s], 0, 0, 0);
                    acc[t2][s] = __builtin_amdgcn_mfma_f32_16x16x32_bf16(a_h[c][t2], blo, acc[t2][s], 0, 0, 0);
                    acc[t2][s] = __builtin_amdgcn_mfma_f32_16x16x32_bf16(a_l[c][t2], bhi, acc[t2][s], 0, 0, 0);
                }
            }
        }
    };

    for (int it = 0; it < nit; it += 2) {
        STEP(wA, wB, it);
        STEP(wB, wA, it + 1);
    }

    // epilogue: partials t_p[kq][s][b][n]; C/D: col=l&15 (n), row=lh*4+i (batch in tile)
    const int n = n0 + lr;
#pragma unroll
    for (int t2 = 0; t2 < 2; ++t2)
#pragma unroll
        for (int s = 0; s < 3; ++s) {
            int brow = w * 32 + t2 * 16 + lh * 4;
            float* tp = t_p + ((size_t)(kq * 3 + s) * BATCH + brow) * NDIM + n;
#pragma unroll
            for (int i = 0; i < 4; ++i) tp[(size_t)i * NDIM] = acc[t2][s][i];
        }
}

// ---------------------------------------------------------------- 5) final: sum kq partials, selu, w2, bc/flag
__global__ __launch_bounds__(256) void k_final(const float* __restrict__ t_p,
                                               const float* __restrict__ bc,
                                               const float* __restrict__ flag,
                                               const float* __restrict__ w2,
                                               float* __restrict__ out, int KS) {
    int idx = blockIdx.x * 256 + threadIdx.x;   // 131072
    int b = idx >> 10, nc = idx & 1023;
    size_t n4 = (size_t)nc * 4;
    f32x4 ts[3] = {};
    for (int kq = 0; kq < KS; ++kq)
#pragma unroll
        for (int s = 0; s < 3; ++s)
            ts[s] += *(const f32x4*)(t_p + ((size_t)(kq * 3 + s) * BATCH + b) * NDIM + n4);
    f32x4 bcv = *(const f32x4*)(bc + n4);
    f32x4 fl  = *(const f32x4*)(flag + n4);
    const float* wp = w2 + (size_t)nc * 12;
    f32x4 o;
#pragma unroll
    for (int j = 0; j < 4; ++j) {
        float sum = selu_f(ts[0][j]) * wp[j * 3 + 0]
                  + selu_f(ts[1][j]) * wp[j * 3 + 1]
                  + selu_f(ts[2][j]) * wp[j * 3 + 2];
        o[j] = bcv[j] + sum * fl[j];
    }
    *(f32x4*)(out + (size_t)b * NDIM + n4) = o;
}

// ---------------------------------------------------------------- launch
extern "C" void kernel_launch(void* const* d_in, const int* in_sizes, int n_in,
                              void* d_out, int out_size, void* d_ws, size_t ws_size,
                              hipStream_t stream) {
    const float* x    = (const float*)d_in[0];
    const float* bc   = (const float*)d_in[1];
    const float* flag = (const float*)d_in[2];
    const int*   rows = (const int*)d_in[3];
    const int*   cols = (const int*)d_in[4];
    const float* vals = (const float*)d_in[5];
    const float* W1   = (const float*)d_in[6];
    const float* w2   = (const float*)d_in[7];
    float* out = (float*)d_out;

    char* ws = (char*)d_ws;
    float*    xt  = (float*)(ws);                    // 2 MB
    float*    y_p = (float*)(ws + (2u  << 20));      // 8 MB  (128 slices x 16K f32)
    ushort_t* Ahi = (ushort_t*)(ws + (10u << 20));   // 1 MB
    ushort_t* Alo = (ushort_t*)(ws + (11u << 20));   // 1 MB
    float*    t_p = (float*)(ws + (12u << 20));      // KS * 6 MB

    const int KS = (ws_size >= (38u << 20)) ? 4 : 2; // k-split tier by scratch size
    const int klen = NDIM / KS;

    k_transpose<<<dim3(NDIM / 32, BATCH / 32), 256, 0, stream>>>(x, xt);
    k_spmv<<<dim3(32, 4), 256, 0, stream>>>(rows, cols, vals, xt, y_p);
    k_prep<<<256, 256, 0, stream>>>(y_p, bc, flag, Ahi, Alo);
    k_gemm<<<dim3(NDIM / 16, KS), 256, 0, stream>>>(W1, Ahi, Alo, t_p, klen);
    k_final<<<512, 256, 0, stream>>>(t_p, bc, flag, w2, out, KS);
}

// Round 6
// 352.082 us; speedup vs baseline: 1.3516x; 1.3516x over previous
//
#include <hip/hip_runtime.h>
#include <math.h>

#define NDIM 4096
#define NNZ_C 110592
#define BATCH 128

typedef unsigned short ushort_t;
typedef _Float16 f16_t;
typedef __attribute__((ext_vector_type(4))) float f32x4;
typedef __attribute__((ext_vector_type(8))) _Float16 f16x8;

// ---------------------------------------------------------------- helpers
__device__ __forceinline__ float selu_f(float x) {
    const float scale = 1.0507009873554804934193349852946f;
    const float alpha = 1.6732632423543772848170429916717f;
    return x > 0.0f ? scale * x : scale * alpha * expm1f(x);
}

__device__ __forceinline__ void gload_lds16(const ushort_t* g, char* l) {
    __builtin_amdgcn_global_load_lds(
        (const __attribute__((address_space(1))) unsigned int*)g,
        (__attribute__((address_space(3))) unsigned int*)l, 16, 0, 0);
}

// ---------------------------------------------------------------- 1) densify B to fp16 (CAS add handles duplicate (r,c) entries)
__global__ __launch_bounds__(256) void k_densify(const int* __restrict__ rows,
                                                 const int* __restrict__ cols,
                                                 const float* __restrict__ vals,
                                                 ushort_t* __restrict__ Bd) {
    int e = blockIdx.x * 256 + threadIdx.x;
    int r = rows[e], c = cols[e];
    float v = vals[e];
    size_t idx = (size_t)r * NDIM + c;
    unsigned* base = (unsigned*)(Bd + (idx & ~(size_t)1));
    const bool hi = (idx & 1) != 0;
    unsigned old = *base, assumed;
    do {
        assumed = old;
        ushort_t h = hi ? (ushort_t)(assumed >> 16) : (ushort_t)(assumed & 0xffffu);
        float cur = (float)__builtin_bit_cast(f16_t, h);
        ushort_t nh = __builtin_bit_cast(ushort_t, (f16_t)(cur + v));
        unsigned nw = hi ? ((assumed & 0x0000ffffu) | ((unsigned)nh << 16))
                         : ((assumed & 0xffff0000u) | (unsigned)nh);
        old = atomicCAS(base, assumed, nw);
    } while (old != assumed);
}

// ---------------------------------------------------------------- 2) x -> fp16 A-frags  [(m>>3)*128 + b]*8 + (m&7)
__global__ __launch_bounds__(256) void k_prepx(const float* __restrict__ x,
                                               ushort_t* __restrict__ Ax) {
    int idx = blockIdx.x * 256 + threadIdx.x;   // 65536
    int b = idx >> 9, kc = idx & 511;
    f32x4 v0 = *(const f32x4*)(x + (size_t)b * NDIM + kc * 8);
    f32x4 v1 = *(const f32x4*)(x + (size_t)b * NDIM + kc * 8 + 4);
    f16x8 h;
#pragma unroll
    for (int j = 0; j < 4; ++j) { h[j] = (f16_t)v0[j]; h[4 + j] = (f16_t)v1[j]; }
    *(f16x8*)(Ax + ((size_t)kc * BATCH + b) * 8) = h;
}

// ---------------------------------------------------------------- 3) spmv as dense GEMM + fused x1 epilogue
// y[b][r] = sum_c Bd[r][c] x[b][c];  Ax1[r][b] = fp16(bc[r] + y*flag[r])  (A-frag layout)
// grid 256 r-tiles, 256 thr = 4 waves, wave w = batch rows [w*32,+32).
// LDS 2 x 8KB: plane P(0..7) = 32-k chunk, lane-linear (global_load_lds order == read order).
__global__ __launch_bounds__(256, 2) void k_spgemm(const ushort_t* __restrict__ Bd,
                                                   const ushort_t* __restrict__ Ax,
                                                   const float* __restrict__ bc,
                                                   const float* __restrict__ flag,
                                                   ushort_t* __restrict__ Ax1) {
    __shared__ __align__(16) char lds[16384];
    const int tid = threadIdx.x;
    const int w = tid >> 6, l = tid & 63;
    const int lr = l & 15, lh = l >> 4;
    const int r0 = blockIdx.x * 16;

    f32x4 acc[2] = {};

    const ushort_t* src[2];
#pragma unroll
    for (int i = 0; i < 2; ++i) {
        int C = i * 256 + tid;
        int r = C & 15, k8 = (C >> 4) & 3, P = C >> 6;
        src[i] = Bd + (size_t)(r0 + r) * NDIM + P * 32 + k8 * 8;
    }
    const size_t arow0 = (size_t)(w * 32 + lr) * 8;
    const size_t arow1 = (size_t)(w * 32 + 16 + lr) * 8;

    // prologue: stage it=0 into buf0
#pragma unroll
    for (int i = 0; i < 2; ++i)
        gload_lds16(src[i], lds + (i * 4 + w) * 1024);

    for (int it = 0; it < 16; ++it) {
        const int cur = it & 1;
        if (it + 1 < 16) {
#pragma unroll
            for (int i = 0; i < 2; ++i)
                gload_lds16(src[i] + (it + 1) * 256, lds + (1 - cur) * 8192 + (i * 4 + w) * 1024);
            asm volatile("s_waitcnt vmcnt(2)" ::: "memory");
        } else {
            asm volatile("s_waitcnt vmcnt(0)" ::: "memory");
        }
        __builtin_amdgcn_s_barrier();
        __builtin_amdgcn_sched_barrier(0);
#pragma unroll
        for (int c = 0; c < 8; ++c) {
            size_t kcg = (size_t)it * 32 + c * 4 + lh;
            f16x8 a0 = *(const f16x8*)(Ax + kcg * 1024 + arow0);
            f16x8 a1 = *(const f16x8*)(Ax + kcg * 1024 + arow1);
            f16x8 bf = *(const f16x8*)(lds + cur * 8192 + c * 1024 + l * 16);
            acc[0] = __builtin_amdgcn_mfma_f32_16x16x32_f16(a0, bf, acc[0], 0, 0, 0);
            acc[1] = __builtin_amdgcn_mfma_f32_16x16x32_f16(a1, bf, acc[1], 0, 0, 0);
        }
        __builtin_amdgcn_s_barrier();
        __builtin_amdgcn_sched_barrier(0);
    }

    // fused epilogue: x1 = bc + y*flag -> fp16 A-frag [(r>>3)*128+b]*8 + (r&7)
    const int r = r0 + lr;
    const float bcv = bc[r], fl = flag[r];
    const size_t fbase = (size_t)(r >> 3) * (BATCH * 8) + (r & 7);
#pragma unroll
    for (int t2 = 0; t2 < 2; ++t2) {
#pragma unroll
        for (int i = 0; i < 4; ++i) {
            int b = w * 32 + t2 * 16 + lh * 4 + i;
            Ax1[fbase + (size_t)b * 8] =
                __builtin_bit_cast(ushort_t, (f16_t)(bcv + acc[t2][i] * fl));
        }
    }
}

// ---------------------------------------------------------------- 4) main fused GEMM, fp16, 8 waves, dbuf LDS, 1 barrier/iter
// grid 256 (n0 = bid*16). 512 thr = 8 waves; wave w = batch rows [w*16,+16).
// Per iter (256 k): W1 f32 tile 48x256 -> regs (6 dwordx4/thr) -> cvt f16 -> LDS.
// LDS: 2 bufs x 24 planes x 1KB. Plane P = s*8 + c32 (wave w writes planes {w, 8+w, 16+w}).
// Writes AND reads are lane-linear (byte = P*1024 + l*16): conflict-free.
// __launch_bounds__(512,2): ensure >=2 blocks/CU so one block's staging overlaps
// another's MFMA (round-2 lesson: 1 block/CU lockstep = idle memory pipe).
__global__ __launch_bounds__(512, 2) void k_gemm(const float* __restrict__ W1,
                                                 const ushort_t* __restrict__ Ax1,
                                                 const float* __restrict__ bc,
                                                 const float* __restrict__ flag,
                                                 const float* __restrict__ w2,
                                                 float* __restrict__ out) {
    __shared__ __align__(16) char lds[49152];
    const int tid = threadIdx.x;
    const int w = tid >> 6, l = tid & 63;
    const int lr = l & 15, lh = l >> 4;
    const int n0 = blockIdx.x * 16;

    f32x4 acc[3] = {};

    // staging: u=0..2 -> plane P = u*8 + w (s = u, c32 = w); chunk = l (linear)
    // global: W1[s=u][n0 + (l&15)][w*32 + (l>>4)*8 .. +8)  (16 segments x 128B per wave)
    const float* gsrc[3];
    int ldst[3];
#pragma unroll
    for (int u = 0; u < 3; ++u) {
        gsrc[u] = W1 + ((size_t)u * NDIM + n0 + lr) * NDIM + w * 32 + lh * 8;
        ldst[u] = (u * 8 + w) * 1024 + l * 16;
    }
    const size_t arow = (size_t)(w * 16 + lr) * 8;

    f32x4 wv[6];
    // prologue: load tile 0
#pragma unroll
    for (int u = 0; u < 3; ++u) {
        wv[2 * u]     = *(const f32x4*)(gsrc[u]);
        wv[2 * u + 1] = *(const f32x4*)(gsrc[u] + 4);
    }

#pragma unroll 1
    for (int it = 0; it < 16; ++it) {
        char* buf = lds + (it & 1) * 24576;
        // W phase: cvt + write (buf[it&1]; laggards read the other buffer)
#pragma unroll
        for (int u = 0; u < 3; ++u) {
            f16x8 h;
#pragma unroll
            for (int j = 0; j < 4; ++j) {
                h[j]     = (f16_t)wv[2 * u][j];
                h[4 + j] = (f16_t)wv[2 * u + 1][j];
            }
            *(f16x8*)(buf + ldst[u]) = h;
        }
        // issue next W tile (stays in flight across the raw barrier)
        if (it + 1 < 16) {
            const size_t off = (size_t)(it + 1) * 256;
#pragma unroll
            for (int u = 0; u < 3; ++u) {
                wv[2 * u]     = *(const f32x4*)(gsrc[u] + off);
                wv[2 * u + 1] = *(const f32x4*)(gsrc[u] + off + 4);
            }
        }
        __builtin_amdgcn_sched_barrier(0);
        asm volatile("s_waitcnt lgkmcnt(0)" ::: "memory");
        __builtin_amdgcn_s_barrier();
        __builtin_amdgcn_sched_barrier(0);

        // R phase: 8 c-chunks x 3 s, one-c-ahead A prefetch (Ax1 is L2-resident)
        f16x8 a_cur = *(const f16x8*)(Ax1 + ((size_t)it * 32 + lh) * 1024 + arow);
#pragma unroll
        for (int c = 0; c < 8; ++c) {
            f16x8 a_nxt;
            if (c < 7)
                a_nxt = *(const f16x8*)(Ax1 + ((size_t)it * 32 + (c + 1) * 4 + lh) * 1024 + arow);
#pragma unroll
            for (int s = 0; s < 3; ++s) {
                f16x8 bf = *(const f16x8*)(buf + (s * 8 + c) * 1024 + l * 16);
                acc[s] = __builtin_amdgcn_mfma_f32_16x16x32_f16(a_cur, bf, acc[s], 0, 0, 0);
            }
            a_cur = a_nxt;
        }
    }

    // fused epilogue: C/D col = l&15 (n), row = lh*4+i (batch within wave tile)
    const int n = n0 + lr;
    const float bcv = bc[n], fl = flag[n];
    const float w20 = w2[n * 3 + 0], w21 = w2[n * 3 + 1], w22 = w2[n * 3 + 2];
#pragma unroll
    for (int i = 0; i < 4; ++i) {
        int b = w * 16 + lh * 4 + i;
        float sum = selu_f(acc[0][i]) * w20 + selu_f(acc[1][i]) * w21
                  + selu_f(acc[2][i]) * w22;
        out[(size_t)b * NDIM + n] = bcv + sum * fl;
    }
}

// ---------------------------------------------------------------- launch
extern "C" void kernel_launch(void* const* d_in, const int* in_sizes, int n_in,
                              void* d_out, int out_size, void* d_ws, size_t ws_size,
                              hipStream_t stream) {
    const float* x    = (const float*)d_in[0];
    const float* bc   = (const float*)d_in[1];
    const float* flag = (const float*)d_in[2];
    const int*   rows = (const int*)d_in[3];
    const int*   cols = (const int*)d_in[4];
    const float* vals = (const float*)d_in[5];
    const float* W1   = (const float*)d_in[6];
    const float* w2   = (const float*)d_in[7];
    float* out = (float*)d_out;

    char* ws = (char*)d_ws;
    ushort_t* Ax  = (ushort_t*)(ws);               // 1 MB (x fp16 A-frags)
    ushort_t* Ax1 = (ushort_t*)(ws + (1u << 20));  // 1 MB (x1 fp16 A-frags)
    ushort_t* Bd  = (ushort_t*)(ws + (2u << 20));  // 32 MB (dense B fp16)

    hipMemsetAsync(Bd, 0, (size_t)NDIM * NDIM * sizeof(ushort_t), stream);
    k_densify<<<NNZ_C / 256, 256, 0, stream>>>(rows, cols, vals, Bd);
    k_prepx<<<256, 256, 0, stream>>>(x, Ax);
    k_spgemm<<<NDIM / 16, 256, 0, stream>>>(Bd, Ax, bc, flag, Ax1);
    k_gemm<<<NDIM / 16, 512, 0, stream>>>(W1, Ax1, bc, flag, w2, out);
}